// Round 10
// baseline (97.910 us; speedup 1.0000x reference)
//
#include <hip/hip_runtime.h>

// Involution: x(2,64,64,256) f32
//   t    = relu(BN(x @ w1 + b1))            (8192 x 64)
//   kern = t @ w2 + b2                      (8192 x 784), 784 = 49 taps * 16 groups
//   out[p][c] = sum_kk kern[p][kk*16 + c%16] * x_zpad[p + tap(kk)][c]
// d_out = [ out : 2097152 floats | kern : 6422528 floats ]
//
// Round-10: occupancy probe. Same 16-px tile / 512 blocks as r6/r9, but
// 512-thread blocks (8 waves): waves 4-7 join staging, phase-4 GEMM and
// apply. 16 waves/CU (vs 8) with per-block fixed costs unchanged.
// __launch_bounds__(512,4) caps VGPR at 128 so 2 blocks/CU co-reside.

typedef __attribute__((ext_vector_type(8))) short short8;   // 8 bf16 = 4 VGPR
typedef __attribute__((ext_vector_type(4))) float f32x4;

#define OUT_ELEMS 2097152
#define W2S_OFF 0                       // ushort[49*2*64*8]  (100352 B) frag order
#define W1S_OFF 131072                  // ushort[4*8*64*8]   (32768 B)  frag order
#define BNS_OFF (131072 + 32768)        // float[64] scale
#define BNH_OFF (BNS_OFF + 256)         // float[64] shift

static __device__ __forceinline__ ushort f2bf(float f) {
    union { float f; unsigned u; } v; v.f = f;
    return (ushort)((v.u + 0x7FFFu + ((v.u >> 16) & 1u)) >> 16);   // RNE
}

// ---------------------------------------------------------------------------
// prep: weights -> bf16 in MFMA B-frag layout (into d_ws).
//   w2s[((kg*2+ks)*64+lane)*8+e] = bf16(w2[k][n]), n=kg*16+(lane&15),
//                                  k=ks*32+(lane>>4)*8+e
//   w1s[((nt*8+ks)*64+lane)*8+e] = bf16(w1[k][n]), n=nt*16+(lane&15), same k
//   bns[d]=gamma*rsqrt(var+eps), bnh[d]=beta+(b1-mu)*bns
// ---------------------------------------------------------------------------
__global__ __launch_bounds__(256)
void prep(const float* __restrict__ w1, const float* __restrict__ w2,
          const float* __restrict__ b1, const float* __restrict__ gamma_,
          const float* __restrict__ beta_, const float* __restrict__ mu_,
          const float* __restrict__ var_, char* __restrict__ base)
{
    const int g = blockIdx.x * 256 + threadIdx.x;
    ushort* w2s = (ushort*)(base + W2S_OFF);
    ushort* w1s = (ushort*)(base + W1S_OFF);
    float*  bns = (float*)(base + BNS_OFF);
    float*  bnh = (float*)(base + BNH_OFF);
    if (g < 50176) {
        const int e = g & 7, lane = (g >> 3) & 63, kgks = g >> 9;
        const int kg = kgks >> 1, ks = kgks & 1;
        const int n = kg * 16 + (lane & 15);
        const int k = ks * 32 + ((lane >> 4) << 3) + e;
        w2s[g] = f2bf(w2[k * 784 + n]);
    } else if (g < 66560) {
        const int e2 = g - 50176;
        const int e = e2 & 7, lane = (e2 >> 3) & 63, ntks = e2 >> 9;
        const int nt = ntks >> 3, ks = ntks & 7;
        const int n = nt * 16 + (lane & 15);
        const int k = ks * 32 + ((lane >> 4) << 3) + e;
        w1s[e2] = f2bf(w1[k * 64 + n]);
    } else if (g < 66624) {
        const int d = g - 66560;
        const float s = gamma_[d] * rsqrtf(var_[d] + 1e-3f);
        bns[d] = s;
        bnh[d] = beta_[d] + (b1[d] - mu_[d]) * s;
    }
}

// ---------------------------------------------------------------------------
// invol_fused: grid 512 (XCD-swizzled: xcd owns px [xcd*1024,+1024)),
// 512 threads (8 waves). Block = 16-px row-segment. Phases (3 barriers):
//   1. stage x(16x256) -> bf16 xb (XOR-swz), all 8 waves        [barrier]
//   2. t = BN/ReLU(x @ w1s): waves 0-3 (one n-block each) -> tb [barrier]
//   3. hoist phase-4 A-frags from tb (all 8 waves)
//   4. kern = t @ w2s + b2: wave wv does kg = wv, wv+8, ... -> global + kl
//                                                               [barrier]
//   5. apply (branchless): wave wv owns px wv*2..+1, lane owns 4 consecutive
//      channels; 8 masked float4 x loads per kh serve 2 px x 7 taps; kern
//      from kl (4 distinct b128 addrs -> banks 0..15, conflict-free).
// ---------------------------------------------------------------------------
#define FMA4(A, K, X) \
    A.x = fmaf(K.x, X.x, A.x); A.y = fmaf(K.y, X.y, A.y); \
    A.z = fmaf(K.z, X.z, A.z); A.w = fmaf(K.w, X.w, A.w);

__global__ __launch_bounds__(512, 4)
void invol_fused(const float* __restrict__ x, const char* __restrict__ base,
                 const float* __restrict__ b2, float* __restrict__ kern_out,
                 float* __restrict__ out)
{
    __shared__ __align__(16) union {
        ushort xb[4096];    // 8 KB (phases 1-2)
        float  kl[12544];   // 16*784 f32 = 50176 B (phases 4-5)
    } u;
    __shared__ __align__(16) ushort tb[1024];   // 2 KB, phases 2-4

    const ushort* w2s = (const ushort*)(base + W2S_OFF);
    const ushort* w1s = (const ushort*)(base + W1S_OFF);
    const float*  bns = (const float*)(base + BNS_OFF);
    const float*  bnh = (const float*)(base + BNH_OFF);

    const int tid  = threadIdx.x;
    const int lane = tid & 63;
    const int wv   = tid >> 6;            // 0..7
    const int bid  = blockIdx.x;          // 0..511
    const int pb   = ((bid & 7) << 10) + ((bid >> 3) << 4);   // 16-px base
    const int b  = pb >> 12;
    const int h  = (pb >> 6) & 63;
    const int w0 = pb & 63;               // multiple of 16

    // ---- phase 1: stage x tile (16px x 256c) -> bf16 LDS, swizzled ----
#pragma unroll
    for (int i = 0; i < 2; ++i) {
        const int f4 = tid + 512 * i;     // 0..1023
        const int px = f4 >> 6;           // 0..15
        const int c0 = (f4 & 63) * 4;
        const float4 v = *(const float4*)(x + (size_t)(pb + px) * 256 + c0);
        ushort4 hh;
        hh.x = f2bf(v.x); hh.y = f2bf(v.y); hh.z = f2bf(v.z); hh.w = f2bf(v.w);
        const int byte = ((px << 9) + (c0 << 1)) ^ ((px & 7) << 4);
        *(ushort4*)((char*)u.xb + byte) = hh;
    }
    __syncthreads();

    const int qlane = lane >> 4;          // 0..3
    const int mrow  = lane & 15;
    const int aswz  = (mrow & 7) << 4;

    // ---- phase 2: t = BN/ReLU(x @ w1s); waves 0-3, one 16-col n-block each ----
    if (wv < 4) {
        f32x4 acc = {0.f, 0.f, 0.f, 0.f};
#pragma unroll
        for (int ks = 0; ks < 8; ++ks) {
            const short8 a = *(const short8*)((const char*)u.xb +
                              (((mrow << 9) + ((ks * 32 + qlane * 8) << 1)) ^ aswz));
            const short8 bv = *(const short8*)(w1s + ((wv * 8 + ks) * 64 + lane) * 8);
            acc = __builtin_amdgcn_mfma_f32_16x16x32_bf16(a, bv, acc, 0, 0, 0);
        }
        // C/D: col = lane&15, row = qlane*4 + r
        const int col = wv * 16 + mrow;
        const float s = bns[col], sh = bnh[col];
#pragma unroll
        for (int r = 0; r < 4; ++r) {
            const int row = qlane * 4 + r;
            const float tv = fmaxf(fmaf(acc[r], s, sh), 0.f);
            const int byte = ((row << 7) + (col << 1)) ^ ((row & 7) << 4);
            *(ushort*)((char*)tb + byte) = f2bf(tv);
        }
    }
    __syncthreads();   // tb complete; all xb reads done -> kl may overwrite xb

    // ---- phase 3: hoist phase-4 A-frags from tb (all waves, no barrier) ----
    const short8 a0 = *(const short8*)((const char*)tb +
                        (((mrow << 7) + (qlane << 4)) ^ aswz));
    const short8 a1 = *(const short8*)((const char*)tb +
                        (((mrow << 7) + 64 + (qlane << 4)) ^ aswz));

    // ---- phase 4: kern = t @ w2s + b2 -> global + kl; wave wv: kg=wv,wv+8,.. ----
    for (int kg = wv; kg < 49; kg += 8) {
        const short8 bv0 = *(const short8*)(w2s + (size_t)((kg * 2 + 0) * 64 + lane) * 8);
        const short8 bv1 = *(const short8*)(w2s + (size_t)((kg * 2 + 1) * 64 + lane) * 8);
        f32x4 c = {0.f, 0.f, 0.f, 0.f};
        c = __builtin_amdgcn_mfma_f32_16x16x32_bf16(a0, bv0, c, 0, 0, 0);
        c = __builtin_amdgcn_mfma_f32_16x16x32_bf16(a1, bv1, c, 0, 0, 0);
        const int n = kg * 16 + mrow;
        const float bias = b2[n];
#pragma unroll
        for (int r = 0; r < 4; ++r) {
            const int row = qlane * 4 + r;
            const float val = c[r] + bias;
            kern_out[(size_t)(pb + row) * 784 + n] = val;
            u.kl[row * 784 + n] = val;
        }
    }
    __syncthreads();

    // ---- phase 5: apply (branchless); wave wv owns px wv*2, wv*2+1 ----
    const int c0  = lane * 4;             // 4 consecutive channels
    const int g0  = c0 & 15;
    const int w0w = w0 + wv * 2;
    const float* xbase = x + ((size_t)b << 20);

    float msk[8]; int colc[8];
#pragma unroll
    for (int j = 0; j < 8; ++j) {
        const int cw = w0w + j - 3;
        msk[j]  = ((unsigned)cw < 64u) ? 1.0f : 0.0f;
        colc[j] = (min(max(cw, 0), 63) << 8) + c0;
    }

    float4 acc4[2];
    acc4[0] = make_float4(0.f, 0.f, 0.f, 0.f);
    acc4[1] = make_float4(0.f, 0.f, 0.f, 0.f);

#pragma unroll
    for (int kh = 0; kh < 7; ++kh) {
        const int hh = h + kh - 3;
        const float rm = ((unsigned)hh < 64u) ? 1.0f : 0.0f;
        const int hc = min(max(hh, 0), 63);
        const float* xr = xbase + ((size_t)hc << 14);
        float4 xv[8];
#pragma unroll
        for (int j = 0; j < 8; ++j) {
            xv[j] = *(const float4*)(xr + colc[j]);
            const float s = msk[j] * rm;
            xv[j].x *= s; xv[j].y *= s; xv[j].z *= s; xv[j].w *= s;
        }
#pragma unroll
        for (int p = 0; p < 2; ++p) {
            const float* kr = u.kl + (wv * 2 + p) * 784 + kh * 112 + g0;
#pragma unroll
            for (int kw = 0; kw < 7; ++kw) {
                const float4 kv = *(const float4*)(kr + kw * 16);
                FMA4(acc4[p], kv, xv[p + kw]);
            }
        }
    }
#pragma unroll
    for (int p = 0; p < 2; ++p)
        *(float4*)(out + (size_t)(pb + wv * 2 + p) * 256 + c0) = acc4[p];
}

extern "C" void kernel_launch(void* const* d_in, const int* in_sizes, int n_in,
                              void* d_out, int out_size, void* d_ws, size_t ws_size,
                              hipStream_t stream)
{
    const float* x      = (const float*)d_in[0];
    const float* w1     = (const float*)d_in[1];
    const float* b1     = (const float*)d_in[2];
    const float* gamma_ = (const float*)d_in[3];
    const float* beta_  = (const float*)d_in[4];
    const float* mu_    = (const float*)d_in[5];
    const float* var_   = (const float*)d_in[6];
    const float* w2     = (const float*)d_in[7];
    const float* b2     = (const float*)d_in[8];

    float* out  = (float*)d_out;
    float* kern = out + OUT_ELEMS;
    char*  base = (char*)d_ws;     // prepped weights in scratch; re-poisoned
                                   // each launch, prep rewrites them.

    prep<<<261, 256, 0, stream>>>(w1, w2, b1, gamma_, beta_, mu_, var_, base);
    invol_fused<<<512, 512, 0, stream>>>(x, base, b2, kern, out);
}